// Round 2
// baseline (808.956 us; speedup 1.0000x reference)
//
#include <hip/hip_runtime.h>
#include <stdint.h>

// CTC forward loss, B=512, T=1024, C=256, L=64, S=129, blank=C-1.
// One wave (64 lanes) per batch element. Lane i holds alpha[2i], alpha[2i+1];
// lane 63 additionally alpha[128]. Cross-state deps via one __shfl_up.
//
// R2/R3 history: per-step global_load_lds + manual vmcnt(31) pipelining was
// latency-serialized at ~1870 cyc/step (799-808us, 672 GB/s = 8% HBM) in BOTH
// the compiler-visible-gather and asm-invisible-gather variants: one wait per
// time-step degenerates to one loaded HBM round-trip per step if anything
// (compiler waitcnt pass or HW) turns the counted wait into a drain.
//
// R4 change: chunked double-buffer so the WORST case is amortized. Two 32-row
// LDS buffers (64 KiB). Per chunk: issue 32 DMAs for chunk c+1, one
// s_waitcnt vmcnt(32) (chunk c resident, chunk c+1 still in flight), then 32
// unrolled update steps gathering from chunk c via plain ds_reads. Even a
// pessimistic compiler-inserted vmcnt(0) before the first gather costs one
// drain per 32 steps (~30-60 cyc/step amortized), not per step. Buffer reuse
// is single-wave-safe: chunk c-1's gather values were consumed (registers)
// before chunk c+1's DMAs overwrite its buffer.

#define EPS 1e-7f
#define NEG -1e30f

constexpr int Bb = 512;
constexpr int Tt = 1024;
constexpr int Cc = 256;
constexpr int Ll = 64;
constexpr int BLANK = Cc - 1;
constexpr int CH = 32;           // rows per chunk (32 x 1KB = 32 KiB/buffer)
constexpr int NCH = Tt / CH;     // 32 chunks

__device__ __forceinline__ void dma_row(const float* __restrict__ g,
                                        float* l) {
    // 64 lanes x 16B -> LDS base + lane*16 (wave-uniform base, contiguous).
    __builtin_amdgcn_global_load_lds(
        (const __attribute__((address_space(1))) void*)g,
        (__attribute__((address_space(3))) void*)l, 16, 0, 0);
}

__global__ __launch_bounds__(64, 1) void ctc_fwd_kernel(
    const int* __restrict__ y_true,   // [B, L] int32
    const float* __restrict__ y_pred, // [B, T, C] float32 probabilities
    float* __restrict__ out)          // [B] float32
{
    const int b = blockIdx.x;
    const int lane = threadIdx.x; // 0..63

    const float* __restrict__ row0 = y_pred + (size_t)b * Tt * Cc;

    __shared__ float ring[2 * CH * Cc]; // 64 KiB: buf0 rows, buf1 rows

    // Label for odd state 2*lane+1. Consume it (shfl) BEFORE issuing DMAs so
    // the compiler's wait for this load retires before the DMA queue fills.
    const int lab = y_true[b * Ll + lane];
    const int lab_prev = __shfl_up(lab, 1);
    const bool allow = (lane == 0) ? true : (lab != lab_prev);

    // ---- prologue: issue chunk 0 -> buf0, chunk 1 -> buf1 ----
    for (int r = 0; r < CH; ++r)
        dma_row(row0 + r * Cc + lane * 4, &ring[r * Cc]);
    for (int r = 0; r < CH; ++r)
        dma_row(row0 + (CH + r) * Cc + lane * 4, &ring[(CH + r) * Cc]);

    // chunk 0 resident; chunk 1's 32 loads may remain outstanding.
    asm volatile("s_waitcnt vmcnt(32)" ::: "memory");

    float ae, ao, a128;
    {
        const float pl0 = ring[lab];
        const float pb0 = ring[BLANK];
        ae = (lane == 0) ? __logf(pb0 + EPS) : NEG; // alpha[2i]
        ao = (lane == 0) ? __logf(pl0 + EPS) : NEG; // alpha[2i+1]
        a128 = NEG;                                 // alpha[128] (lane 63)
    }

    auto update = [&](float gl, float gb) {
        const float lpl = __logf(gl + EPS);
        const float lpb = __logf(gb + EPS);
        float ao_up = __shfl_up(ao, 1);
        if (lane == 0) ao_up = NEG;

        // even state s=2i: from alpha[2i], alpha[2i-1]; emits blank
        const float m2 = fmaxf(ae, ao_up);
        const float ne =
            m2 + __logf(__expf(ae - m2) + __expf(ao_up - m2)) + lpb;

        // odd state s=2i+1: from alpha[2i+1], alpha[2i], (allow) alpha[2i-1]
        const float a3 = allow ? ao_up : NEG;
        const float m3 = fmaxf(fmaxf(ao, ae), a3);
        const float no =
            m3 +
            __logf(__expf(ao - m3) + __expf(ae - m3) + __expf(a3 - m3)) +
            lpl;

        // state 128 (lane 63): from alpha[128], alpha[127]; emits blank
        const float m1 = fmaxf(a128, ao);
        const float n128 =
            m1 + __logf(__expf(a128 - m1) + __expf(ao - m1)) + lpb;

        ae = ne;
        ao = no;
        a128 = n128;
    };

    // ---- chunk 0: steps t = 1..31 from buf0 ----
#pragma unroll
    for (int r = 1; r < CH; ++r)
        update(ring[r * Cc + lab], ring[r * Cc + BLANK]);

    // ---- chunks 1..NCH-1 ----
    for (int c = 1; c < NCH; ++c) {
        const float* buf = &ring[(c & 1) * CH * Cc];
        float* nbuf = &ring[((c + 1) & 1) * CH * Cc];
        if (c + 1 < NCH) {
            const float* src = row0 + (size_t)(c + 1) * CH * Cc;
            for (int r = 0; r < CH; ++r)
                dma_row(src + r * Cc + lane * 4, nbuf + r * Cc);
            // chunk c resident; chunk c+1's 32 loads may remain outstanding.
            asm volatile("s_waitcnt vmcnt(32)" ::: "memory");
        } else {
            asm volatile("s_waitcnt vmcnt(0)" ::: "memory");
        }
#pragma unroll
        for (int r = 0; r < CH; ++r)
            update(buf[r * Cc + lab], buf[r * Cc + BLANK]);
    }

    // sequence ends on final blank (state 128) or final label (state 127)
    if (lane == 63) {
        const float m = fmaxf(a128, ao);
        out[b] = -(m + __logf(__expf(a128 - m) + __expf(ao - m)));
    }
}

extern "C" void kernel_launch(void* const* d_in, const int* in_sizes, int n_in,
                              void* d_out, int out_size, void* d_ws,
                              size_t ws_size, hipStream_t stream) {
    const int* y_true = (const int*)d_in[0];     // [512,64] int32
    const float* y_pred = (const float*)d_in[1]; // [512,1024,256] fp32
    float* out = (float*)d_out;                  // [512] fp32

    ctc_fwd_kernel<<<dim3(Bb), dim3(64), 0, stream>>>(y_true, y_pred, out);
}